// Round 1
// baseline (407.114 us; speedup 1.0000x reference)
//
#include <hip/hip_runtime.h>
#include <hip/hip_bf16.h>

typedef unsigned short ushort_t;
typedef unsigned int uint_t;

typedef __bf16 bf16x8 __attribute__((ext_vector_type(8)));
typedef float f32x4 __attribute__((ext_vector_type(4)));
typedef ushort_t us8 __attribute__((ext_vector_type(8)));

__device__ __forceinline__ float bf2f(ushort_t u) {
    return __uint_as_float(((uint_t)u) << 16);
}
__device__ __forceinline__ ushort_t f2bf(float f) {
    uint_t x = __float_as_uint(f);
    uint_t r = (x + 0x7FFFu + ((x >> 16) & 1u)) >> 16;
    return (ushort_t)r;
}
__device__ __forceinline__ float sigmoidf_fast(float x) {
    return 1.0f / (1.0f + __expf(-x));
}

// Geometry constants
#define PP 12544          // pixels per image plane = 112*112 (= 98*128)
#define PLANE 25690112ULL // elements per k-plane of U2t = 8*256*12544

// ---------------------------------------------------------------------------
// Kernel 1: permute+transpose W2 (fp32 256x768) -> W2t (bf16 768x256).
// (verbatim verified)
// ---------------------------------------------------------------------------
__global__ __launch_bounds__(256) void permute_w2(const float* __restrict__ W2,
                                                  ushort_t* __restrict__ W2t) {
    int i = blockIdx.x * 256 + threadIdx.x;   // 768*256 total
    int np = i >> 8;        // n' in [0,768)
    int k  = i & 255;       // k  in [0,256)
    int kk  = np >> 8;      // 0..2
    int rem = np & 255;
    int dir = rem >> 7;
    int d   = rem & 127;
    int oc = dir * 384 + d * 3 + kk;
    W2t[np * 256 + k] = f2bf(W2[k * 768 + oc]);
}

// ---------------------------------------------------------------------------
// Kernel 2: fused patch-extract + GEMM1 (K=12, register weights) + SRU scan
// over Wp. Block = (hp,b), thread = channel (dir,d). Writes:
//   H1a[b][p][ch] (bf16, GEMM A operand), p = hp*112+wp  (tid-coalesced)
//   U2t plane3[b][ch][p] = sqrt(2)*h  -- NO LDS transpose: for a fixed
//   thread (=ch), consecutive tt are consecutive plane-3 addresses, so we
//   accumulate 8 steps in registers and issue one aligned 16B store per 8.
//   (v2: hbuf 57.8KB LDS removed -> LDS 5.4KB, occupancy 2->4 blocks/CU.)
// ---------------------------------------------------------------------------
__global__ __launch_bounds__(256, 4) void scan1(const float* __restrict__ x,
                                                const float* __restrict__ W1,
                                                const float* __restrict__ wc1,
                                                const float* __restrict__ b1,
                                                ushort_t* __restrict__ H1a,
                                                ushort_t* __restrict__ U2t) {
    __shared__ float patch[112 * 12];       // 5376 B only
    const int n1 = blockIdx.x;
    const int hp = n1 >> 3, b = n1 & 7;
    const int tid = threadIdx.x;
    const float SCALE_X = 1.41421356237309515f;

    for (int e = tid; e < 1344; e += 256) {
        int c = e / 448;
        int rem = e % 448;
        int wh = rem / 224;
        int pos = rem % 224;            // 2*wp + ww
        float v = x[((b * 3 + c) * 224 + (2 * hp + wh)) * 224 + pos];
        patch[(pos >> 1) * 12 + c * 4 + wh * 2 + (pos & 1)] = v;
    }

    float4 w[12];
    const float4* W1v = (const float4*)W1;
#pragma unroll
    for (int j = 0; j < 12; ++j) w[j] = W1v[j * 256 + tid];

    const float vf = wc1[tid],       vr = wc1[256 + tid];
    const float bfv = b1[tid],       brv = b1[256 + tid];
    const int dir = tid >> 7;        // wave-uniform (waves 0-1 fwd, 2-3 bwd)

    __syncthreads();

    // plane-3 base for this thread's channel: U2t[3][b][ch=tid][hp*112 + *]
    const size_t p3base = 3 * PLANE + ((size_t)(b * 256 + tid)) * PP
                        + (size_t)hp * 112;
    const size_t h1base = ((size_t)b * PP + (size_t)hp * 112) * 256 + tid;

    float cst = 0.0f;
    for (int tb = 0; tb < 14; ++tb) {          // 14 * 8 = 112 steps
        ushort_t hr[8];                         // static-indexed -> registers
#pragma unroll
        for (int i = 0; i < 8; ++i) {
            const int t = tb * 8 + i;
            const int tt = dir ? (111 - t) : t;
            const float4* pp = (const float4*)(patch + tt * 12);
            float4 p0 = pp[0], p1 = pp[1], p2 = pp[2];
            float pj[12] = {p0.x, p0.y, p0.z, p0.w, p1.x, p1.y, p1.z, p1.w,
                            p2.x, p2.y, p2.z, p2.w};
            float u0 = 0.f, u1 = 0.f, u2 = 0.f, u3 = 0.f;
#pragma unroll
            for (int j = 0; j < 12; ++j) {
                float pv = pj[j];
                u0 = fmaf(w[j].x, pv, u0);
                u1 = fmaf(w[j].y, pv, u1);
                u2 = fmaf(w[j].z, pv, u2);
                u3 = fmaf(w[j].w, pv, u3);
            }
            float f = sigmoidf_fast(u1 + vf * cst + bfv);
            cst = f * cst + (1.0f - f) * u0;
            float r = sigmoidf_fast(u2 + vr * cst + brv);
            float h = r * cst + (1.0f - r) * u3;
            H1a[h1base + (size_t)tt * 256] = f2bf(h);
            hr[i] = f2bf(h * SCALE_X);
        }
        // One aligned 16B store per 8 steps. dir=0: tt block [tb*8, tb*8+7]
        // in order; dir=1: tt block [104-tb*8, 111-tb*8], element j holds
        // hr[7-j]. Branch is wave-uniform.
        const int tbase = dir ? (104 - tb * 8) : (tb * 8);
        us8 v;
        if (dir) {
            v[0] = hr[7]; v[1] = hr[6]; v[2] = hr[5]; v[3] = hr[4];
            v[4] = hr[3]; v[5] = hr[2]; v[6] = hr[1]; v[7] = hr[0];
        } else {
            v[0] = hr[0]; v[1] = hr[1]; v[2] = hr[2]; v[3] = hr[3];
            v[4] = hr[4]; v[5] = hr[5]; v[6] = hr[6]; v[7] = hr[7];
        }
        *(us8*)(U2t + p3base + tbase) = v;
    }
}

// ---------------------------------------------------------------------------
// Kernel 3: bf16 MFMA GEMM: H1a(M x 256) @ W2t^T, M=100352 (m = b*PP+p).
// 128x128 tile. K-unroll x2: two BK=32 sub-tiles staged per barrier pair
// (identical per-sub-tile layout to the verified r5 kernel; barriers 8 -> 4).
// Epilogue: per-lane aligned ushort4 stores into U2t k-plane [k][b][ch][p].
// ---------------------------------------------------------------------------
__global__ __launch_bounds__(256) void gemm2(const ushort_t* __restrict__ A,
                                             const ushort_t* __restrict__ Bt,
                                             ushort_t* __restrict__ U2t) {
    __shared__ ushort_t As[2][128 * 32];   // [half][row][k] 64B rows, 8 KB each
    __shared__ ushort_t Bs[2][128 * 32];   // total 32 KB
    const int m0 = blockIdx.y * 128;
    const int bb = blockIdx.y / 98;        // batch index (m0 == bb*PP + p0)
    const int p0 = (blockIdx.y % 98) * 128;
    const int n0 = blockIdx.x * 128;
    const int kidx = n0 >> 8;              // 0..2
    const int ch0  = n0 & 255;             // 0 or 128
    const int tid = threadIdx.x;
    const int w = tid >> 6, lane = tid & 63;
    const int wm = w >> 1, wn = w & 1;
    const int lr = lane >> 2;
    const int lc = (lane & 3) * 8;
    const int ln16 = lane & 15;
    const int k8 = (lane >> 4) * 8;

    f32x4 acc[4][4] = {};

    for (int kb = 0; kb < 256; kb += 64) {
        if (kb) __syncthreads();
#pragma unroll
        for (int h = 0; h < 2; ++h) {
#pragma unroll
            for (int q = 0; q < 2; ++q) {
                int r = w * 32 + q * 16;   // wave-uniform base row of 1KB chunk
                const ushort_t* gA = A + (size_t)(m0 + r + lr) * 256 + kb + h * 32 + lc;
                __builtin_amdgcn_global_load_lds(
                    (const __attribute__((address_space(1))) uint_t*)gA,
                    (__attribute__((address_space(3))) uint_t*)(As[h] + r * 32), 16, 0, 0);
                const ushort_t* gB = Bt + (size_t)(n0 + r + lr) * 256 + kb + h * 32 + lc;
                __builtin_amdgcn_global_load_lds(
                    (const __attribute__((address_space(1))) uint_t*)gB,
                    (__attribute__((address_space(3))) uint_t*)(Bs[h] + r * 32), 16, 0, 0);
            }
        }
        __syncthreads();

#pragma unroll
        for (int h = 0; h < 2; ++h) {
            bf16x8 af[4], bf[4];
#pragma unroll
            for (int i = 0; i < 4; ++i) {
                af[i] = *(const bf16x8*)(As[h] + (wm * 64 + i * 16 + ln16) * 32 + k8);
                bf[i] = *(const bf16x8*)(Bs[h] + (wn * 64 + i * 16 + ln16) * 32 + k8);
            }
#pragma unroll
            for (int i = 0; i < 4; ++i)
#pragma unroll
                for (int j = 0; j < 4; ++j)
                    acc[i][j] = __builtin_amdgcn_mfma_f32_16x16x32_bf16(
                        af[i], bf[j], acc[i][j], 0, 0, 0);
        }
    }

    // Epilogue: C/D layout col(N)=lane&15, row(M)=(lane>>4)*4+reg.
    const int rq = (lane >> 4) * 4;
    const size_t planeBase = (size_t)kidx * PLANE + (size_t)(bb * 256 + ch0) * PP;
#pragma unroll
    for (int i = 0; i < 4; ++i) {
        int p = p0 + wm * 64 + i * 16 + rq;
#pragma unroll
        for (int j = 0; j < 4; ++j) {
            int ch_l = wn * 64 + j * 16 + ln16;
            ushort4 v;
            v.x = f2bf(acc[i][j][0]);
            v.y = f2bf(acc[i][j][1]);
            v.z = f2bf(acc[i][j][2]);
            v.w = f2bf(acc[i][j][3]);
            *(ushort4*)(U2t + planeBase + (size_t)ch_l * PP + p) = v;
        }
    }
}

// ---------------------------------------------------------------------------
// Kernel 4: SRU scan over hp, writes d_out directly (b,ch,hp,wp).
// 256 threads = 2 ch x 128 lanes (wp>=112 idle), wave-uniform dir,
// grid (128,8) = 1024 blocks. Depth-3 shift-register prefetch: loads for
// t+3 issue while computing t -> ~3 iterations of latency slack.
// ---------------------------------------------------------------------------
__global__ __launch_bounds__(256) void scan2(const ushort_t* __restrict__ U2t,
                                             const float* __restrict__ wc2,
                                             const float* __restrict__ b2,
                                             float* __restrict__ out) {
    const int cb = blockIdx.x;             // 0..127
    const int b  = blockIdx.y;             // 0..7
    const int tid = threadIdx.x;
    const int ch = cb * 2 + (tid >> 7);    // 0..255
    const int wp = tid & 127;
    if (wp >= 112) return;
    const int dir = ch >> 7;

    const float vf = wc2[ch],  vr = wc2[256 + ch];
    const float bfv = b2[ch],  brv = b2[256 + ch];

    const int tt0 = dir ? 111 : 0;
    const long dstep = dir ? -112 : 112;   // hp stride in U2t planes
    const long ostep = dir ? -112 : 112;   // hp stride in out

    const ushort_t* P = U2t;
    long q    = (long)((size_t)(b * 256 + ch) * PP) + tt0 * 112 + wp;
    long oOff = (long)((size_t)(b * 256 + ch) * 112 + tt0) * 112 + wp;

    // Preload t=0,1,2 (x=t, y=t+1, z=t+2); q ends pointing at t+2.
    ushort_t x0 = P[q], x1 = P[PLANE + q], x2 = P[2 * PLANE + q], x3 = P[3 * PLANE + q];
    q += dstep;
    ushort_t y0 = P[q], y1 = P[PLANE + q], y2 = P[2 * PLANE + q], y3 = P[3 * PLANE + q];
    q += dstep;
    ushort_t z0 = P[q], z1 = P[PLANE + q], z2 = P[2 * PLANE + q], z3 = P[3 * PLANE + q];

    float cst = 0.0f;
    for (int t = 0; t < 112; ++t) {
        // issue loads for t+3 (clamped to t=111's address when past the end)
        long qn = q + ((t < 109) ? dstep : 0);
        ushort_t w0 = P[qn], w1 = P[PLANE + qn], w2 = P[2 * PLANE + qn], w3 = P[3 * PLANE + qn];

        float u0 = bf2f(x0), u1 = bf2f(x1), u2v = bf2f(x2);
        float xp = bf2f(x3);               // already scaled by sqrt(2)
        float f = sigmoidf_fast(u1 + vf * cst + bfv);
        cst = f * cst + (1.0f - f) * u0;
        float r = sigmoidf_fast(u2v + vr * cst + brv);
        out[oOff] = r * cst + (1.0f - r) * xp;

        x0 = y0; x1 = y1; x2 = y2; x3 = y3;
        y0 = z0; y1 = z1; y2 = z2; y3 = z3;
        z0 = w0; z1 = w1; z2 = w2; z3 = w3;
        q = qn;
        oOff += ostep;
    }
}

// ---------------------------------------------------------------------------
// Launch. Workspace layout (bytes):
//   H1a bf16 [b][p][ch] 8*12544*256       @ 0          (51,380,224)
//   U2t bf16 4 planes [k][b][ch][p]       @ 51380224   (205,520,896)
//   W2t bf16 768*256                      @ 256901120  (393,216)
// ---------------------------------------------------------------------------
extern "C" void kernel_launch(void* const* d_in, const int* in_sizes, int n_in,
                              void* d_out, int out_size, void* d_ws, size_t ws_size,
                              hipStream_t stream) {
    const float* x   = (const float*)d_in[0];
    const float* W1  = (const float*)d_in[1];
    const float* wc1 = (const float*)d_in[2];
    const float* b1  = (const float*)d_in[3];
    const float* W2  = (const float*)d_in[4];
    const float* wc2 = (const float*)d_in[5];
    const float* b2  = (const float*)d_in[6];
    float* out = (float*)d_out;

    char* ws = (char*)d_ws;
    ushort_t* H1a = (ushort_t*)(ws);
    ushort_t* U2t = (ushort_t*)(ws + 51380224);
    ushort_t* W2t = (ushort_t*)(ws + 51380224 + 205520896);

    permute_w2<<<768, 256, 0, stream>>>(W2, W2t);
    scan1<<<896, 256, 0, stream>>>(x, W1, wc1, b1, H1a, U2t);
    gemm2<<<dim3(6, 784), 256, 0, stream>>>(H1a, W2t, U2t);
    scan2<<<dim3(128, 8), 256, 0, stream>>>(U2t, wc2, b2, out);
}

// Round 2
// 382.413 us; speedup vs baseline: 1.0646x; 1.0646x over previous
//
#include <hip/hip_runtime.h>
#include <hip/hip_bf16.h>

typedef unsigned short ushort_t;
typedef unsigned int uint_t;

typedef __bf16 bf16x8 __attribute__((ext_vector_type(8)));
typedef float f32x4 __attribute__((ext_vector_type(4)));
typedef ushort_t us8 __attribute__((ext_vector_type(8)));

__device__ __forceinline__ float bf2f(ushort_t u) {
    return __uint_as_float(((uint_t)u) << 16);
}
__device__ __forceinline__ ushort_t f2bf(float f) {
    uint_t x = __float_as_uint(f);
    uint_t r = (x + 0x7FFFu + ((x >> 16) & 1u)) >> 16;
    return (ushort_t)r;
}
__device__ __forceinline__ float sigmoidf_fast(float x) {
    return 1.0f / (1.0f + __expf(-x));
}

// Geometry constants
#define PP 12544          // pixels per image plane = 112*112 (= 98*128)
#define PLANE 25690112ULL // elements per k-plane of U2t = 8*256*12544

// ---------------------------------------------------------------------------
// Kernel 1: permute+transpose W2 (fp32 256x768) -> W2t (bf16 768x256).
// (verbatim verified)
// ---------------------------------------------------------------------------
__global__ __launch_bounds__(256) void permute_w2(const float* __restrict__ W2,
                                                  ushort_t* __restrict__ W2t) {
    int i = blockIdx.x * 256 + threadIdx.x;   // 768*256 total
    int np = i >> 8;        // n' in [0,768)
    int k  = i & 255;       // k  in [0,256)
    int kk  = np >> 8;      // 0..2
    int rem = np & 255;
    int dir = rem >> 7;
    int d   = rem & 127;
    int oc = dir * 384 + d * 3 + kk;
    W2t[np * 256 + k] = f2bf(W2[k * 768 + oc]);
}

// ---------------------------------------------------------------------------
// Kernel 2: fused patch-extract + GEMM1 (K=12, register weights) + SRU scan
// over Wp. Block = (hp,b), thread = channel (dir,d).
// v3: writes ONLY H1a[b][p][ch] (bf16, tid-coalesced 512B/wave). The plane-3
// transpose (scan2's xprime) now happens inside gemm2 from its As LDS tiles,
// so this kernel has no LDS transpose buffer (LDS 5.6 KB) and no scattered
// stores (v2's 16B/lane scatter caused partial-line RMW: FETCH 30MB,
// WRITE 242MB). Occupancy is grid-limited (896 blocks, ~3.5/CU resident).
// ---------------------------------------------------------------------------
__global__ __launch_bounds__(256) void scan1(const float* __restrict__ x,
                                             const float* __restrict__ W1,
                                             const float* __restrict__ wc1,
                                             const float* __restrict__ b1,
                                             ushort_t* __restrict__ H1a) {
    __shared__ float patch[112 * 12];       // 5376 B only
    const int n1 = blockIdx.x;
    const int hp = n1 >> 3, b = n1 & 7;
    const int tid = threadIdx.x;

    for (int e = tid; e < 1344; e += 256) {
        int c = e / 448;
        int rem = e % 448;
        int wh = rem / 224;
        int pos = rem % 224;            // 2*wp + ww
        float v = x[((b * 3 + c) * 224 + (2 * hp + wh)) * 224 + pos];
        patch[(pos >> 1) * 12 + c * 4 + wh * 2 + (pos & 1)] = v;
    }

    float4 w[12];
    const float4* W1v = (const float4*)W1;
#pragma unroll
    for (int j = 0; j < 12; ++j) w[j] = W1v[j * 256 + tid];

    const float vf = wc1[tid],       vr = wc1[256 + tid];
    const float bfv = b1[tid],       brv = b1[256 + tid];
    const int dir = tid >> 7;        // wave-uniform (waves 0-1 fwd, 2-3 bwd)

    __syncthreads();

    const size_t h1base = ((size_t)b * PP + (size_t)hp * 112) * 256 + tid;

    float cst = 0.0f;
    for (int t = 0; t < 112; ++t) {
        const int tt = dir ? (111 - t) : t;
        const float4* pp = (const float4*)(patch + tt * 12);
        float4 p0 = pp[0], p1 = pp[1], p2 = pp[2];
        float pj[12] = {p0.x, p0.y, p0.z, p0.w, p1.x, p1.y, p1.z, p1.w,
                        p2.x, p2.y, p2.z, p2.w};
        float u0 = 0.f, u1 = 0.f, u2 = 0.f, u3 = 0.f;
#pragma unroll
        for (int j = 0; j < 12; ++j) {
            float pv = pj[j];
            u0 = fmaf(w[j].x, pv, u0);
            u1 = fmaf(w[j].y, pv, u1);
            u2 = fmaf(w[j].z, pv, u2);
            u3 = fmaf(w[j].w, pv, u3);
        }
        float f = sigmoidf_fast(u1 + vf * cst + bfv);
        cst = f * cst + (1.0f - f) * u0;
        float r = sigmoidf_fast(u2 + vr * cst + brv);
        float h = r * cst + (1.0f - r) * u3;
        H1a[h1base + (size_t)tt * 256] = f2bf(h);
    }
}

// ---------------------------------------------------------------------------
// Kernel 3: bf16 MFMA GEMM: H1a(M x 256) @ W2t^T, M=100352 (m = b*PP+p).
// 128x128 tile. K-unroll x2: two BK=32 sub-tiles staged per barrier pair.
// Epilogue: per-lane aligned ushort4 stores into U2t k-plane [k][b][ch][p].
// v3 addition: plane-3 ([3][b][ch][p] = raw H1 bf16 bits, scan2 scales by
// sqrt2) is written here by transposing the already-staged As tile. Block
// x (=0..3) handles kb-chunk x*64. Per thread: fixed ch' = kb + (tid&63),
// 32 consecutive p (wave-uniform chunk tid>>6); 32 ds_read_u16 (~2-way bank
// aliasing = free) -> 4 back-to-back us8 stores = 64B contiguous; the 4
// waves jointly cover each ch's full 256B (two 128-aligned lines) within a
// few hundred cycles -> no partial-line RMW.
// ---------------------------------------------------------------------------
__global__ __launch_bounds__(256) void gemm2(const ushort_t* __restrict__ A,
                                             const ushort_t* __restrict__ Bt,
                                             ushort_t* __restrict__ U2t) {
    __shared__ ushort_t As[2][128 * 32];   // [half][row][k] 64B rows, 8 KB each
    __shared__ ushort_t Bs[2][128 * 32];   // total 32 KB
    const int m0 = blockIdx.y * 128;
    const int bb = blockIdx.y / 98;        // batch index (m0 == bb*PP + p0)
    const int p0 = (blockIdx.y % 98) * 128;
    const int n0 = blockIdx.x * 128;
    const int kidx = n0 >> 8;              // 0..2
    const int ch0  = n0 & 255;             // 0 or 128
    const int tid = threadIdx.x;
    const int w = tid >> 6, lane = tid & 63;
    const int wm = w >> 1, wn = w & 1;
    const int lr = lane >> 2;
    const int lc = (lane & 3) * 8;
    const int ln16 = lane & 15;
    const int k8 = (lane >> 4) * 8;

    f32x4 acc[4][4] = {};

    for (int kb = 0; kb < 256; kb += 64) {
        if (kb) __syncthreads();
#pragma unroll
        for (int h = 0; h < 2; ++h) {
#pragma unroll
            for (int q = 0; q < 2; ++q) {
                int r = w * 32 + q * 16;   // wave-uniform base row of 1KB chunk
                const ushort_t* gA = A + (size_t)(m0 + r + lr) * 256 + kb + h * 32 + lc;
                __builtin_amdgcn_global_load_lds(
                    (const __attribute__((address_space(1))) uint_t*)gA,
                    (__attribute__((address_space(3))) uint_t*)(As[h] + r * 32), 16, 0, 0);
                const ushort_t* gB = Bt + (size_t)(n0 + r + lr) * 256 + kb + h * 32 + lc;
                __builtin_amdgcn_global_load_lds(
                    (const __attribute__((address_space(1))) uint_t*)gB,
                    (__attribute__((address_space(3))) uint_t*)(Bs[h] + r * 32), 16, 0, 0);
            }
        }
        __syncthreads();

#pragma unroll
        for (int h = 0; h < 2; ++h) {
            bf16x8 af[4], bf[4];
#pragma unroll
            for (int i = 0; i < 4; ++i) {
                af[i] = *(const bf16x8*)(As[h] + (wm * 64 + i * 16 + ln16) * 32 + k8);
                bf[i] = *(const bf16x8*)(Bs[h] + (wn * 64 + i * 16 + ln16) * 32 + k8);
            }
#pragma unroll
            for (int i = 0; i < 4; ++i)
#pragma unroll
                for (int j = 0; j < 4; ++j)
                    acc[i][j] = __builtin_amdgcn_mfma_f32_16x16x32_bf16(
                        af[i], bf[j], acc[i][j], 0, 0, 0);
        }

        // Plane-3 transpose write-out from the staged As tile (raw bits).
        if (blockIdx.x < 4 && kb == (int)blockIdx.x * 64) {
            const int cl = tid & 63;          // ch-local 0..63 within kb chunk
            const int pc = tid >> 6;          // wave-uniform p chunk (0..3)
            const int hh = cl >> 5;           // As half
            const int cc = cl & 31;           // k within half
            const size_t p3 = 3 * PLANE
                            + (size_t)(bb * 256 + kb + cl) * PP + p0 + pc * 32;
#pragma unroll
            for (int j8 = 0; j8 < 4; ++j8) {
                us8 v;
#pragma unroll
                for (int j = 0; j < 8; ++j)
                    v[j] = As[hh][(pc * 32 + j8 * 8 + j) * 32 + cc];
                *(us8*)(U2t + p3 + j8 * 8) = v;
            }
        }
    }

    // Epilogue: C/D layout col(N)=lane&15, row(M)=(lane>>4)*4+reg.
    const int rq = (lane >> 4) * 4;
    const size_t planeBase = (size_t)kidx * PLANE + (size_t)(bb * 256 + ch0) * PP;
#pragma unroll
    for (int i = 0; i < 4; ++i) {
        int p = p0 + wm * 64 + i * 16 + rq;
#pragma unroll
        for (int j = 0; j < 4; ++j) {
            int ch_l = wn * 64 + j * 16 + ln16;
            ushort4 v;
            v.x = f2bf(acc[i][j][0]);
            v.y = f2bf(acc[i][j][1]);
            v.z = f2bf(acc[i][j][2]);
            v.w = f2bf(acc[i][j][3]);
            *(ushort4*)(U2t + planeBase + (size_t)ch_l * PP + p) = v;
        }
    }
}

// ---------------------------------------------------------------------------
// Kernel 4: SRU scan over hp, writes d_out directly (b,ch,hp,wp).
// 256 threads = 2 ch x 128 lanes (wp>=112 idle), wave-uniform dir,
// grid (128,8) = 1024 blocks. Depth-3 shift-register prefetch: loads for
// t+3 issue while computing t -> ~3 iterations of latency slack.
// v3: plane-3 holds raw h bits; scale by sqrt2 here (1 f32 mul/step).
// ---------------------------------------------------------------------------
__global__ __launch_bounds__(256) void scan2(const ushort_t* __restrict__ U2t,
                                             const float* __restrict__ wc2,
                                             const float* __restrict__ b2,
                                             float* __restrict__ out) {
    const int cb = blockIdx.x;             // 0..127
    const int b  = blockIdx.y;             // 0..7
    const int tid = threadIdx.x;
    const int ch = cb * 2 + (tid >> 7);    // 0..255
    const int wp = tid & 127;
    if (wp >= 112) return;
    const int dir = ch >> 7;
    const float SCALE_X = 1.41421356237309515f;

    const float vf = wc2[ch],  vr = wc2[256 + ch];
    const float bfv = b2[ch],  brv = b2[256 + ch];

    const int tt0 = dir ? 111 : 0;
    const long dstep = dir ? -112 : 112;   // hp stride in U2t planes
    const long ostep = dir ? -112 : 112;   // hp stride in out

    const ushort_t* P = U2t;
    long q    = (long)((size_t)(b * 256 + ch) * PP) + tt0 * 112 + wp;
    long oOff = (long)((size_t)(b * 256 + ch) * 112 + tt0) * 112 + wp;

    // Preload t=0,1,2 (x=t, y=t+1, z=t+2); q ends pointing at t+2.
    ushort_t x0 = P[q], x1 = P[PLANE + q], x2 = P[2 * PLANE + q], x3 = P[3 * PLANE + q];
    q += dstep;
    ushort_t y0 = P[q], y1 = P[PLANE + q], y2 = P[2 * PLANE + q], y3 = P[3 * PLANE + q];
    q += dstep;
    ushort_t z0 = P[q], z1 = P[PLANE + q], z2 = P[2 * PLANE + q], z3 = P[3 * PLANE + q];

    float cst = 0.0f;
    for (int t = 0; t < 112; ++t) {
        // issue loads for t+3 (clamped to t=111's address when past the end)
        long qn = q + ((t < 109) ? dstep : 0);
        ushort_t w0 = P[qn], w1 = P[PLANE + qn], w2 = P[2 * PLANE + qn], w3 = P[3 * PLANE + qn];

        float u0 = bf2f(x0), u1 = bf2f(x1), u2v = bf2f(x2);
        float xp = bf2f(x3) * SCALE_X;     // scale xprime here (v3)
        float f = sigmoidf_fast(u1 + vf * cst + bfv);
        cst = f * cst + (1.0f - f) * u0;
        float r = sigmoidf_fast(u2v + vr * cst + brv);
        out[oOff] = r * cst + (1.0f - r) * xp;

        x0 = y0; x1 = y1; x2 = y2; x3 = y3;
        y0 = z0; y1 = z1; y2 = z2; y3 = z3;
        z0 = w0; z1 = w1; z2 = w2; z3 = w3;
        q = qn;
        oOff += ostep;
    }
}

// ---------------------------------------------------------------------------
// Launch. Workspace layout (bytes):
//   H1a bf16 [b][p][ch] 8*12544*256       @ 0          (51,380,224)
//   U2t bf16 4 planes [k][b][ch][p]       @ 51380224   (205,520,896)
//   W2t bf16 768*256                      @ 256901120  (393,216)
// ---------------------------------------------------------------------------
extern "C" void kernel_launch(void* const* d_in, const int* in_sizes, int n_in,
                              void* d_out, int out_size, void* d_ws, size_t ws_size,
                              hipStream_t stream) {
    const float* x   = (const float*)d_in[0];
    const float* W1  = (const float*)d_in[1];
    const float* wc1 = (const float*)d_in[2];
    const float* b1  = (const float*)d_in[3];
    const float* W2  = (const float*)d_in[4];
    const float* wc2 = (const float*)d_in[5];
    const float* b2  = (const float*)d_in[6];
    float* out = (float*)d_out;

    char* ws = (char*)d_ws;
    ushort_t* H1a = (ushort_t*)(ws);
    ushort_t* U2t = (ushort_t*)(ws + 51380224);
    ushort_t* W2t = (ushort_t*)(ws + 51380224 + 205520896);

    permute_w2<<<768, 256, 0, stream>>>(W2, W2t);
    scan1<<<896, 256, 0, stream>>>(x, W1, wc1, b1, H1a);
    gemm2<<<dim3(6, 784), 256, 0, stream>>>(H1a, W2t, U2t);
    scan2<<<dim3(128, 8), 256, 0, stream>>>(U2t, wc2, b2, out);
}

// Round 3
// 377.332 us; speedup vs baseline: 1.0789x; 1.0135x over previous
//
#include <hip/hip_runtime.h>
#include <hip/hip_bf16.h>

typedef unsigned short ushort_t;
typedef unsigned int uint_t;

typedef __bf16 bf16x8 __attribute__((ext_vector_type(8)));
typedef float f32x4 __attribute__((ext_vector_type(4)));
typedef ushort_t us8 __attribute__((ext_vector_type(8)));

__device__ __forceinline__ float bf2f(ushort_t u) {
    return __uint_as_float(((uint_t)u) << 16);
}
__device__ __forceinline__ ushort_t f2bf(float f) {
    uint_t x = __float_as_uint(f);
    uint_t r = (x + 0x7FFFu + ((x >> 16) & 1u)) >> 16;
    return (ushort_t)r;
}
__device__ __forceinline__ float sigmoidf_fast(float x) {
    return 1.0f / (1.0f + __expf(-x));
}

// Geometry constants
#define PP 12544          // pixels per image plane = 112*112 (= 98*128)
#define PLANE 25690112ULL // elements per k-plane of U2t = 8*256*12544

// ---------------------------------------------------------------------------
// Kernel 1: permute+transpose W2 (fp32 256x768) -> W2t (bf16 768x256).
// (verbatim verified)
// ---------------------------------------------------------------------------
__global__ __launch_bounds__(256) void permute_w2(const float* __restrict__ W2,
                                                  ushort_t* __restrict__ W2t) {
    int i = blockIdx.x * 256 + threadIdx.x;   // 768*256 total
    int np = i >> 8;        // n' in [0,768)
    int k  = i & 255;       // k  in [0,256)
    int kk  = np >> 8;      // 0..2
    int rem = np & 255;
    int dir = rem >> 7;
    int d   = rem & 127;
    int oc = dir * 384 + d * 3 + kk;
    W2t[np * 256 + k] = f2bf(W2[k * 768 + oc]);
}

// ---------------------------------------------------------------------------
// Kernel 2: fused patch-extract + GEMM1 (K=12, register weights) + SRU scan
// over Wp. Block = (hp,b), thread = channel (dir,d). Writes only
// H1a[b][p][ch] (bf16, tid-coalesced). (verbatim from verified v3)
// ---------------------------------------------------------------------------
__global__ __launch_bounds__(256) void scan1(const float* __restrict__ x,
                                             const float* __restrict__ W1,
                                             const float* __restrict__ wc1,
                                             const float* __restrict__ b1,
                                             ushort_t* __restrict__ H1a) {
    __shared__ float patch[112 * 12];       // 5376 B only
    const int n1 = blockIdx.x;
    const int hp = n1 >> 3, b = n1 & 7;
    const int tid = threadIdx.x;

    for (int e = tid; e < 1344; e += 256) {
        int c = e / 448;
        int rem = e % 448;
        int wh = rem / 224;
        int pos = rem % 224;            // 2*wp + ww
        float v = x[((b * 3 + c) * 224 + (2 * hp + wh)) * 224 + pos];
        patch[(pos >> 1) * 12 + c * 4 + wh * 2 + (pos & 1)] = v;
    }

    float4 w[12];
    const float4* W1v = (const float4*)W1;
#pragma unroll
    for (int j = 0; j < 12; ++j) w[j] = W1v[j * 256 + tid];

    const float vf = wc1[tid],       vr = wc1[256 + tid];
    const float bfv = b1[tid],       brv = b1[256 + tid];
    const int dir = tid >> 7;        // wave-uniform (waves 0-1 fwd, 2-3 bwd)

    __syncthreads();

    const size_t h1base = ((size_t)b * PP + (size_t)hp * 112) * 256 + tid;

    float cst = 0.0f;
    for (int t = 0; t < 112; ++t) {
        const int tt = dir ? (111 - t) : t;
        const float4* pp = (const float4*)(patch + tt * 12);
        float4 p0 = pp[0], p1 = pp[1], p2 = pp[2];
        float pj[12] = {p0.x, p0.y, p0.z, p0.w, p1.x, p1.y, p1.z, p1.w,
                        p2.x, p2.y, p2.z, p2.w};
        float u0 = 0.f, u1 = 0.f, u2 = 0.f, u3 = 0.f;
#pragma unroll
        for (int j = 0; j < 12; ++j) {
            float pv = pj[j];
            u0 = fmaf(w[j].x, pv, u0);
            u1 = fmaf(w[j].y, pv, u1);
            u2 = fmaf(w[j].z, pv, u2);
            u3 = fmaf(w[j].w, pv, u3);
        }
        float f = sigmoidf_fast(u1 + vf * cst + bfv);
        cst = f * cst + (1.0f - f) * u0;
        float r = sigmoidf_fast(u2 + vr * cst + brv);
        float h = r * cst + (1.0f - r) * u3;
        H1a[h1base + (size_t)tt * 256] = f2bf(h);
    }
}

// ---------------------------------------------------------------------------
// Kernel 3: bf16 MFMA GEMM: H1a(M x 256) @ W2t^T, M=100352 (m = b*PP+p).
// 128x128 tile, K-unroll x2 (two BK=32 sub-tiles per barrier pair).
// v4: XCD-aware 1-D grid swizzle (T1). 4704 blocks = 8 XCDs x 588 pairs.
// Under round-robin dispatch (xcd = blockIdx & 7), XCD g owns pairs
// [g*588,(g+1)*588) in y-major order: the 6 n-tiles of each m-panel run
// back-to-back on ONE XCD -> each 64KB A-panel fetched once into one L2
// (was: consecutive x-blocks spread over 6 XCDs -> FETCH 3x A = 152MB).
// Bijective since 4704 % 8 == 0.
// Epilogue: per-lane aligned ushort4 stores into U2t k-plane [k][b][ch][p];
// plane-3 ([3][b][ch][p] = raw H1 bits) transposed from staged As tiles by
// blocks nx<4 at kb==nx*64.
// ---------------------------------------------------------------------------
__global__ __launch_bounds__(256) void gemm2(const ushort_t* __restrict__ A,
                                             const ushort_t* __restrict__ Bt,
                                             ushort_t* __restrict__ U2t) {
    __shared__ ushort_t As[2][128 * 32];   // [half][row][k] 64B rows, 8 KB each
    __shared__ ushort_t Bs[2][128 * 32];   // total 32 KB

    // T1 swizzle: blockIdx.x -> (nx, ny), y-major within each XCD's chunk.
    const int l    = blockIdx.x;           // 0..4703
    const int pair = (l & 7) * 588 + (l >> 3);
    const int nx   = pair % 6;             // n-tile 0..5
    const int ny   = pair / 6;             // m-panel 0..783

    const int m0 = ny * 128;
    const int bb = ny / 98;                // batch index (m0 == bb*PP + p0)
    const int p0 = (ny % 98) * 128;
    const int n0 = nx * 128;
    const int kidx = n0 >> 8;              // 0..2
    const int ch0  = n0 & 255;             // 0 or 128
    const int tid = threadIdx.x;
    const int w = tid >> 6, lane = tid & 63;
    const int wm = w >> 1, wn = w & 1;
    const int lr = lane >> 2;
    const int lc = (lane & 3) * 8;
    const int ln16 = lane & 15;
    const int k8 = (lane >> 4) * 8;

    f32x4 acc[4][4] = {};

    for (int kb = 0; kb < 256; kb += 64) {
        if (kb) __syncthreads();
#pragma unroll
        for (int h = 0; h < 2; ++h) {
#pragma unroll
            for (int q = 0; q < 2; ++q) {
                int r = w * 32 + q * 16;   // wave-uniform base row of 1KB chunk
                const ushort_t* gA = A + (size_t)(m0 + r + lr) * 256 + kb + h * 32 + lc;
                __builtin_amdgcn_global_load_lds(
                    (const __attribute__((address_space(1))) uint_t*)gA,
                    (__attribute__((address_space(3))) uint_t*)(As[h] + r * 32), 16, 0, 0);
                const ushort_t* gB = Bt + (size_t)(n0 + r + lr) * 256 + kb + h * 32 + lc;
                __builtin_amdgcn_global_load_lds(
                    (const __attribute__((address_space(1))) uint_t*)gB,
                    (__attribute__((address_space(3))) uint_t*)(Bs[h] + r * 32), 16, 0, 0);
            }
        }
        __syncthreads();

#pragma unroll
        for (int h = 0; h < 2; ++h) {
            bf16x8 af[4], bf[4];
#pragma unroll
            for (int i = 0; i < 4; ++i) {
                af[i] = *(const bf16x8*)(As[h] + (wm * 64 + i * 16 + ln16) * 32 + k8);
                bf[i] = *(const bf16x8*)(Bs[h] + (wn * 64 + i * 16 + ln16) * 32 + k8);
            }
#pragma unroll
            for (int i = 0; i < 4; ++i)
#pragma unroll
                for (int j = 0; j < 4; ++j)
                    acc[i][j] = __builtin_amdgcn_mfma_f32_16x16x32_bf16(
                        af[i], bf[j], acc[i][j], 0, 0, 0);
        }

        // Plane-3 transpose write-out from the staged As tile (raw bits).
        if (nx < 4 && kb == nx * 64) {
            const int cl = tid & 63;          // ch-local 0..63 within kb chunk
            const int pc = tid >> 6;          // wave-uniform p chunk (0..3)
            const int hh = cl >> 5;           // As half
            const int cc = cl & 31;           // k within half
            const size_t p3 = 3 * PLANE
                            + (size_t)(bb * 256 + kb + cl) * PP + p0 + pc * 32;
#pragma unroll
            for (int j8 = 0; j8 < 4; ++j8) {
                us8 v;
#pragma unroll
                for (int j = 0; j < 8; ++j)
                    v[j] = As[hh][(pc * 32 + j8 * 8 + j) * 32 + cc];
                *(us8*)(U2t + p3 + j8 * 8) = v;
            }
        }
    }

    // Epilogue: C/D layout col(N)=lane&15, row(M)=(lane>>4)*4+reg.
    const int rq = (lane >> 4) * 4;
    const size_t planeBase = (size_t)kidx * PLANE + (size_t)(bb * 256 + ch0) * PP;
#pragma unroll
    for (int i = 0; i < 4; ++i) {
        int p = p0 + wm * 64 + i * 16 + rq;
#pragma unroll
        for (int j = 0; j < 4; ++j) {
            int ch_l = wn * 64 + j * 16 + ln16;
            ushort4 v;
            v.x = f2bf(acc[i][j][0]);
            v.y = f2bf(acc[i][j][1]);
            v.z = f2bf(acc[i][j][2]);
            v.w = f2bf(acc[i][j][3]);
            *(ushort4*)(U2t + planeBase + (size_t)ch_l * PP + p) = v;
        }
    }
}

// ---------------------------------------------------------------------------
// Kernel 4: SRU scan over hp, writes d_out directly (b,ch,hp,wp).
// 256 threads = 2 ch x 128 lanes (wp>=112 idle), wave-uniform dir,
// grid (128,8) = 1024 blocks. Depth-3 shift-register prefetch.
// plane-3 holds raw h bits; scale by sqrt2 here (1 f32 mul/step).
// ---------------------------------------------------------------------------
__global__ __launch_bounds__(256) void scan2(const ushort_t* __restrict__ U2t,
                                             const float* __restrict__ wc2,
                                             const float* __restrict__ b2,
                                             float* __restrict__ out) {
    const int cb = blockIdx.x;             // 0..127
    const int b  = blockIdx.y;             // 0..7
    const int tid = threadIdx.x;
    const int ch = cb * 2 + (tid >> 7);    // 0..255
    const int wp = tid & 127;
    if (wp >= 112) return;
    const int dir = ch >> 7;
    const float SCALE_X = 1.41421356237309515f;

    const float vf = wc2[ch],  vr = wc2[256 + ch];
    const float bfv = b2[ch],  brv = b2[256 + ch];

    const int tt0 = dir ? 111 : 0;
    const long dstep = dir ? -112 : 112;   // hp stride in U2t planes
    const long ostep = dir ? -112 : 112;   // hp stride in out

    const ushort_t* P = U2t;
    long q    = (long)((size_t)(b * 256 + ch) * PP) + tt0 * 112 + wp;
    long oOff = (long)((size_t)(b * 256 + ch) * 112 + tt0) * 112 + wp;

    // Preload t=0,1,2 (x=t, y=t+1, z=t+2); q ends pointing at t+2.
    ushort_t x0 = P[q], x1 = P[PLANE + q], x2 = P[2 * PLANE + q], x3 = P[3 * PLANE + q];
    q += dstep;
    ushort_t y0 = P[q], y1 = P[PLANE + q], y2 = P[2 * PLANE + q], y3 = P[3 * PLANE + q];
    q += dstep;
    ushort_t z0 = P[q], z1 = P[PLANE + q], z2 = P[2 * PLANE + q], z3 = P[3 * PLANE + q];

    float cst = 0.0f;
    for (int t = 0; t < 112; ++t) {
        // issue loads for t+3 (clamped to t=111's address when past the end)
        long qn = q + ((t < 109) ? dstep : 0);
        ushort_t w0 = P[qn], w1 = P[PLANE + qn], w2 = P[2 * PLANE + qn], w3 = P[3 * PLANE + qn];

        float u0 = bf2f(x0), u1 = bf2f(x1), u2v = bf2f(x2);
        float xp = bf2f(x3) * SCALE_X;     // scale xprime here
        float f = sigmoidf_fast(u1 + vf * cst + bfv);
        cst = f * cst + (1.0f - f) * u0;
        float r = sigmoidf_fast(u2v + vr * cst + brv);
        out[oOff] = r * cst + (1.0f - r) * xp;

        x0 = y0; x1 = y1; x2 = y2; x3 = y3;
        y0 = z0; y1 = z1; y2 = z2; y3 = z3;
        z0 = w0; z1 = w1; z2 = w2; z3 = w3;
        q = qn;
        oOff += ostep;
    }
}

// ---------------------------------------------------------------------------
// Launch. Workspace layout (bytes):
//   H1a bf16 [b][p][ch] 8*12544*256       @ 0          (51,380,224)
//   U2t bf16 4 planes [k][b][ch][p]       @ 51380224   (205,520,896)
//   W2t bf16 768*256                      @ 256901120  (393,216)
// ---------------------------------------------------------------------------
extern "C" void kernel_launch(void* const* d_in, const int* in_sizes, int n_in,
                              void* d_out, int out_size, void* d_ws, size_t ws_size,
                              hipStream_t stream) {
    const float* x   = (const float*)d_in[0];
    const float* W1  = (const float*)d_in[1];
    const float* wc1 = (const float*)d_in[2];
    const float* b1  = (const float*)d_in[3];
    const float* W2  = (const float*)d_in[4];
    const float* wc2 = (const float*)d_in[5];
    const float* b2  = (const float*)d_in[6];
    float* out = (float*)d_out;

    char* ws = (char*)d_ws;
    ushort_t* H1a = (ushort_t*)(ws);
    ushort_t* U2t = (ushort_t*)(ws + 51380224);
    ushort_t* W2t = (ushort_t*)(ws + 51380224 + 205520896);

    permute_w2<<<768, 256, 0, stream>>>(W2, W2t);
    scan1<<<896, 256, 0, stream>>>(x, W1, wc1, b1, H1a);
    gemm2<<<4704, 256, 0, stream>>>(H1a, W2t, U2t);
    scan2<<<dim3(128, 8), 256, 0, stream>>>(U2t, wc2, b2, out);
}

// Round 4
// 353.187 us; speedup vs baseline: 1.1527x; 1.0684x over previous
//
#include <hip/hip_runtime.h>
#include <hip/hip_bf16.h>

typedef unsigned short ushort_t;
typedef unsigned int uint_t;

typedef __bf16 bf16x8 __attribute__((ext_vector_type(8)));
typedef float f32x4 __attribute__((ext_vector_type(4)));
typedef ushort_t us8 __attribute__((ext_vector_type(8)));

__device__ __forceinline__ float bf2f(ushort_t u) {
    return __uint_as_float(((uint_t)u) << 16);
}
__device__ __forceinline__ ushort_t f2bf(float f) {
    uint_t x = __float_as_uint(f);
    uint_t r = (x + 0x7FFFu + ((x >> 16) & 1u)) >> 16;
    return (ushort_t)r;
}
__device__ __forceinline__ float sigmoidf_fast(float x) {
    return 1.0f / (1.0f + __expf(-x));
}

// Geometry constants
#define PP 12544          // pixels per image plane = 112*112 (= 98*128)
#define PLANE 25690112ULL // elements per k-plane of U2t = 8*256*12544

// ---------------------------------------------------------------------------
// Kernel 1: permute+transpose W2 (fp32 256x768) -> W2t (bf16 768x256).
// (verbatim verified)
// ---------------------------------------------------------------------------
__global__ __launch_bounds__(256) void permute_w2(const float* __restrict__ W2,
                                                  ushort_t* __restrict__ W2t) {
    int i = blockIdx.x * 256 + threadIdx.x;   // 768*256 total
    int np = i >> 8;        // n' in [0,768)
    int k  = i & 255;       // k  in [0,256)
    int kk  = np >> 8;      // 0..2
    int rem = np & 255;
    int dir = rem >> 7;
    int d   = rem & 127;
    int oc = dir * 384 + d * 3 + kk;
    W2t[np * 256 + k] = f2bf(W2[k * 768 + oc]);
}

// ---------------------------------------------------------------------------
// Kernel 2: fused patch-extract + GEMM1 (K=12, register weights) + SRU scan
// over Wp. Block = (hp,b), thread = channel (dir,d). Writes only
// H1a[b][p][ch] (bf16, tid-coalesced). (verbatim verified)
// ---------------------------------------------------------------------------
__global__ __launch_bounds__(256) void scan1(const float* __restrict__ x,
                                             const float* __restrict__ W1,
                                             const float* __restrict__ wc1,
                                             const float* __restrict__ b1,
                                             ushort_t* __restrict__ H1a) {
    __shared__ float patch[112 * 12];       // 5376 B only
    const int n1 = blockIdx.x;
    const int hp = n1 >> 3, b = n1 & 7;
    const int tid = threadIdx.x;

    for (int e = tid; e < 1344; e += 256) {
        int c = e / 448;
        int rem = e % 448;
        int wh = rem / 224;
        int pos = rem % 224;            // 2*wp + ww
        float v = x[((b * 3 + c) * 224 + (2 * hp + wh)) * 224 + pos];
        patch[(pos >> 1) * 12 + c * 4 + wh * 2 + (pos & 1)] = v;
    }

    float4 w[12];
    const float4* W1v = (const float4*)W1;
#pragma unroll
    for (int j = 0; j < 12; ++j) w[j] = W1v[j * 256 + tid];

    const float vf = wc1[tid],       vr = wc1[256 + tid];
    const float bfv = b1[tid],       brv = b1[256 + tid];
    const int dir = tid >> 7;        // wave-uniform (waves 0-1 fwd, 2-3 bwd)

    __syncthreads();

    const size_t h1base = ((size_t)b * PP + (size_t)hp * 112) * 256 + tid;

    float cst = 0.0f;
    for (int t = 0; t < 112; ++t) {
        const int tt = dir ? (111 - t) : t;
        const float4* pp = (const float4*)(patch + tt * 12);
        float4 p0 = pp[0], p1 = pp[1], p2 = pp[2];
        float pj[12] = {p0.x, p0.y, p0.z, p0.w, p1.x, p1.y, p1.z, p1.w,
                        p2.x, p2.y, p2.z, p2.w};
        float u0 = 0.f, u1 = 0.f, u2 = 0.f, u3 = 0.f;
#pragma unroll
        for (int j = 0; j < 12; ++j) {
            float pv = pj[j];
            u0 = fmaf(w[j].x, pv, u0);
            u1 = fmaf(w[j].y, pv, u1);
            u2 = fmaf(w[j].z, pv, u2);
            u3 = fmaf(w[j].w, pv, u3);
        }
        float f = sigmoidf_fast(u1 + vf * cst + bfv);
        cst = f * cst + (1.0f - f) * u0;
        float r = sigmoidf_fast(u2 + vr * cst + brv);
        float h = r * cst + (1.0f - r) * u3;
        H1a[h1base + (size_t)tt * 256] = f2bf(h);
    }
}

// ---------------------------------------------------------------------------
// Kernel 3: bf16 MFMA GEMM: H1a(M x 256) @ W2t^T, M=100352 (m = b*PP+p).
// 128x128 tile, K-unroll x2 (two BK=32 sub-tiles per barrier pair).
// XCD-aware 1-D grid swizzle (T1): 4704 blocks = 8 XCDs x 588 pairs,
// y-major within each XCD chunk so the 6 n-tiles of an m-panel share one
// XCD's L2 (A-panel fetched once). (verbatim from verified v4)
// ---------------------------------------------------------------------------
__global__ __launch_bounds__(256) void gemm2(const ushort_t* __restrict__ A,
                                             const ushort_t* __restrict__ Bt,
                                             ushort_t* __restrict__ U2t) {
    __shared__ ushort_t As[2][128 * 32];   // [half][row][k] 64B rows, 8 KB each
    __shared__ ushort_t Bs[2][128 * 32];   // total 32 KB

    // T1 swizzle: blockIdx.x -> (nx, ny), y-major within each XCD's chunk.
    const int l    = blockIdx.x;           // 0..4703
    const int pair = (l & 7) * 588 + (l >> 3);
    const int nx   = pair % 6;             // n-tile 0..5
    const int ny   = pair / 6;             // m-panel 0..783

    const int m0 = ny * 128;
    const int bb = ny / 98;                // batch index (m0 == bb*PP + p0)
    const int p0 = (ny % 98) * 128;
    const int n0 = nx * 128;
    const int kidx = n0 >> 8;              // 0..2
    const int ch0  = n0 & 255;             // 0 or 128
    const int tid = threadIdx.x;
    const int w = tid >> 6, lane = tid & 63;
    const int wm = w >> 1, wn = w & 1;
    const int lr = lane >> 2;
    const int lc = (lane & 3) * 8;
    const int ln16 = lane & 15;
    const int k8 = (lane >> 4) * 8;

    f32x4 acc[4][4] = {};

    for (int kb = 0; kb < 256; kb += 64) {
        if (kb) __syncthreads();
#pragma unroll
        for (int h = 0; h < 2; ++h) {
#pragma unroll
            for (int q = 0; q < 2; ++q) {
                int r = w * 32 + q * 16;   // wave-uniform base row of 1KB chunk
                const ushort_t* gA = A + (size_t)(m0 + r + lr) * 256 + kb + h * 32 + lc;
                __builtin_amdgcn_global_load_lds(
                    (const __attribute__((address_space(1))) uint_t*)gA,
                    (__attribute__((address_space(3))) uint_t*)(As[h] + r * 32), 16, 0, 0);
                const ushort_t* gB = Bt + (size_t)(n0 + r + lr) * 256 + kb + h * 32 + lc;
                __builtin_amdgcn_global_load_lds(
                    (const __attribute__((address_space(1))) uint_t*)gB,
                    (__attribute__((address_space(3))) uint_t*)(Bs[h] + r * 32), 16, 0, 0);
            }
        }
        __syncthreads();

#pragma unroll
        for (int h = 0; h < 2; ++h) {
            bf16x8 af[4], bf[4];
#pragma unroll
            for (int i = 0; i < 4; ++i) {
                af[i] = *(const bf16x8*)(As[h] + (wm * 64 + i * 16 + ln16) * 32 + k8);
                bf[i] = *(const bf16x8*)(Bs[h] + (wn * 64 + i * 16 + ln16) * 32 + k8);
            }
#pragma unroll
            for (int i = 0; i < 4; ++i)
#pragma unroll
                for (int j = 0; j < 4; ++j)
                    acc[i][j] = __builtin_amdgcn_mfma_f32_16x16x32_bf16(
                        af[i], bf[j], acc[i][j], 0, 0, 0);
        }

        // Plane-3 transpose write-out from the staged As tile (raw bits).
        if (nx < 4 && kb == nx * 64) {
            const int cl = tid & 63;          // ch-local 0..63 within kb chunk
            const int pc = tid >> 6;          // wave-uniform p chunk (0..3)
            const int hh = cl >> 5;           // As half
            const int cc = cl & 31;           // k within half
            const size_t p3 = 3 * PLANE
                            + (size_t)(bb * 256 + kb + cl) * PP + p0 + pc * 32;
#pragma unroll
            for (int j8 = 0; j8 < 4; ++j8) {
                us8 v;
#pragma unroll
                for (int j = 0; j < 8; ++j)
                    v[j] = As[hh][(pc * 32 + j8 * 8 + j) * 32 + cc];
                *(us8*)(U2t + p3 + j8 * 8) = v;
            }
        }
    }

    // Epilogue: C/D layout col(N)=lane&15, row(M)=(lane>>4)*4+reg.
    const int rq = (lane >> 4) * 4;
    const size_t planeBase = (size_t)kidx * PLANE + (size_t)(bb * 256 + ch0) * PP;
#pragma unroll
    for (int i = 0; i < 4; ++i) {
        int p = p0 + wm * 64 + i * 16 + rq;
#pragma unroll
        for (int j = 0; j < 4; ++j) {
            int ch_l = wn * 64 + j * 16 + ln16;
            ushort4 v;
            v.x = f2bf(acc[i][j][0]);
            v.y = f2bf(acc[i][j][1]);
            v.z = f2bf(acc[i][j][2]);
            v.w = f2bf(acc[i][j][3]);
            *(ushort4*)(U2t + planeBase + (size_t)ch_l * PP + p) = v;
        }
    }
}

// ---------------------------------------------------------------------------
// Kernel 4: SRU scan over hp, writes d_out directly (b,ch,hp,wp).
// 256 threads = 2 ch x 128 lanes (wp>=112 idle), wave-uniform dir,
// grid (128,8) = 1024 blocks.
// v5: depth-7 shift-register prefetch (was 3). r3 counters showed scan2
// latency-bound: VALUBusy 44%, BW 24%, occ 36% -- depth-3 gave only ~120cy
// slack vs ~200-300cy L2/HBM latency. Depth 7 = 6 steps ~250-300cy slack.
// 112 = 7*16, so a 7-unrolled body keeps all buf indices static (rule #20).
// plane-3 holds raw h bits; scale by sqrt2 here (1 f32 mul/step).
// ---------------------------------------------------------------------------
__global__ __launch_bounds__(256) void scan2(const ushort_t* __restrict__ U2t,
                                             const float* __restrict__ wc2,
                                             const float* __restrict__ b2,
                                             float* __restrict__ out) {
    const int cb = blockIdx.x;             // 0..127
    const int b  = blockIdx.y;             // 0..7
    const int tid = threadIdx.x;
    const int ch = cb * 2 + (tid >> 7);    // 0..255
    const int wp = tid & 127;
    if (wp >= 112) return;
    const int dir = ch >> 7;
    const float SCALE_X = 1.41421356237309515f;

    const float vf = wc2[ch],  vr = wc2[256 + ch];
    const float bfv = b2[ch],  brv = b2[256 + ch];

    const int tt0 = dir ? 111 : 0;
    const long dstep = dir ? -112 : 112;   // hp stride in U2t planes
    const long ostep = dir ? -112 : 112;   // hp stride in out

    const ushort_t* P = U2t;
    long oOff = (long)((size_t)(b * 256 + ch) * 112 + tt0) * 112 + wp;

    // Depth-7 pipeline: buf[s] holds the 4 plane values for step t with
    // t%7 == s. Preload t=0..5; qp ends at addr(t=6).
    ushort_t buf[7][4];
    long qp = (long)((size_t)(b * 256 + ch) * PP) + tt0 * 112 + wp;
#pragma unroll
    for (int i = 0; i < 6; ++i) {
        buf[i][0] = P[qp];
        buf[i][1] = P[PLANE + qp];
        buf[i][2] = P[2 * PLANE + qp];
        buf[i][3] = P[3 * PLANE + qp];
        qp += dstep;
    }

    float cst = 0.0f;
    for (int tb = 0; tb < 16; ++tb) {
#pragma unroll
        for (int u = 0; u < 7; ++u) {
            const int t = tb * 7 + u;
            // prefetch step t+6 into slot (u+6)%7 (static index); past the
            // end, re-load t=111's row (in-bounds, value unused).
            buf[(u + 6) % 7][0] = P[qp];
            buf[(u + 6) % 7][1] = P[PLANE + qp];
            buf[(u + 6) % 7][2] = P[2 * PLANE + qp];
            buf[(u + 6) % 7][3] = P[3 * PLANE + qp];
            qp += (t < 105) ? dstep : 0;

            float u0 = bf2f(buf[u][0]);
            float u1 = bf2f(buf[u][1]);
            float u2v = bf2f(buf[u][2]);
            float xp = bf2f(buf[u][3]) * SCALE_X;
            float f = sigmoidf_fast(u1 + vf * cst + bfv);
            cst = f * cst + (1.0f - f) * u0;
            float r = sigmoidf_fast(u2v + vr * cst + brv);
            out[oOff] = r * cst + (1.0f - r) * xp;
            oOff += ostep;
        }
    }
}

// ---------------------------------------------------------------------------
// Launch. Workspace layout (bytes):
//   H1a bf16 [b][p][ch] 8*12544*256       @ 0          (51,380,224)
//   U2t bf16 4 planes [k][b][ch][p]       @ 51380224   (205,520,896)
//   W2t bf16 768*256                      @ 256901120  (393,216)
// ---------------------------------------------------------------------------
extern "C" void kernel_launch(void* const* d_in, const int* in_sizes, int n_in,
                              void* d_out, int out_size, void* d_ws, size_t ws_size,
                              hipStream_t stream) {
    const float* x   = (const float*)d_in[0];
    const float* W1  = (const float*)d_in[1];
    const float* wc1 = (const float*)d_in[2];
    const float* b1  = (const float*)d_in[3];
    const float* W2  = (const float*)d_in[4];
    const float* wc2 = (const float*)d_in[5];
    const float* b2  = (const float*)d_in[6];
    float* out = (float*)d_out;

    char* ws = (char*)d_ws;
    ushort_t* H1a = (ushort_t*)(ws);
    ushort_t* U2t = (ushort_t*)(ws + 51380224);
    ushort_t* W2t = (ushort_t*)(ws + 51380224 + 205520896);

    permute_w2<<<768, 256, 0, stream>>>(W2, W2t);
    scan1<<<896, 256, 0, stream>>>(x, W1, wc1, b1, H1a);
    gemm2<<<4704, 256, 0, stream>>>(H1a, W2t, U2t);
    scan2<<<dim3(128, 8), 256, 0, stream>>>(U2t, wc2, b2, out);
}